// Round 3
// baseline (277.223 us; speedup 1.0000x reference)
//
#include <hip/hip_runtime.h>
#include <hip/hip_bf16.h>

#define Sx 256
#define Dx 300
#define Mx 1024
#define CC 5.0f

// workspace layout (float offsets)
#define OFF_REP    0
#define OFF_DEP    307200
#define OFF_HEAD   614400
#define OFF_ATTN   921600
#define OFF_WTFC   1228800   // [300k][300g]
#define OFF_WT12   1318800   // [300k][600g]  g<300: W1 (dep), g>=300: W2 (head)
#define OFF_WTF12  1498800   // [600k][300g]  k<300: Wf1, k>=300: Wf2
#define OFF_BIAS   1678800   // bfc@+0, b1@+304, bf@+608 (each padded to 304)

__device__ __forceinline__ float bf2f(unsigned short u) {
    union { unsigned int i; float f; } v;
    v.i = ((unsigned int)u) << 16;
    return v.f;
}

__device__ __forceinline__ float fast_tanh(float x) {
    float e = __expf(2.0f * x);
    return (e - 1.0f) / (e + 1.0f);
}

// weights ~N(0,0.05): bf16 interp of true bf16 -> all |v|<1; of fp32 halves -> ~2e-10 chance
__device__ __forceinline__ int detect_bf16(const void* w) {
    const unsigned short* u = (const unsigned short*)w;
    int ok = 1;
    #pragma unroll
    for (int t = 0; t < 64; ++t) {
        float v = bf2f(u[t]);
        ok &= (fabsf(v) < 1.0f) ? 1 : 0;
    }
    return ok;
}

__device__ __forceinline__ float ldf(const void* p, int idx, int isbf) {
    return isbf ? bf2f(((const unsigned short*)p)[idx]) : ((const float*)p)[idx];
}

// ---------------------------------------------------------------------------
// k_prep: transpose all 5 weight matrices into fp32 WT layouts + biases.
// grid 501 x 256 thr. blocks 0..499: transpose tiles; block 500: biases.
// ---------------------------------------------------------------------------
__global__ __launch_bounds__(256) void k_prep(
        const void* __restrict__ Wfc, const void* __restrict__ W1,
        const void* __restrict__ W2,  const void* __restrict__ Wf1,
        const void* __restrict__ Wf2, const void* __restrict__ bfc,
        const void* __restrict__ b1,  const void* __restrict__ bfv,
        float* __restrict__ ws) {
    __shared__ float tile[32][33];
    __shared__ int s_isbf;
    if (threadIdx.x == 0) s_isbf = detect_bf16(Wfc);
    __syncthreads();
    const int isbf = s_isbf;
    const int bid = blockIdx.x;
    if (bid == 500) {
        for (int idx = threadIdx.x; idx < 912; idx += 256) {
            int wb = idx / 304, o = idx - wb * 304;
            const void* src = (wb == 0) ? bfc : (wb == 1 ? b1 : bfv);
            ws[OFF_BIAS + idx] = (o < Dx) ? ldf(src, o, isbf) : 0.0f;
        }
        return;
    }
    const int job = bid / 100, t = bid % 100;
    const int tg = t / 10, tk = t % 10;
    const void* src; float* dst; int stride, rowOff, colOff;
    switch (job) {
        case 0:  src = Wfc; dst = ws + OFF_WTFC;  stride = 300; rowOff = 0;   colOff = 0;   break;
        case 1:  src = W1;  dst = ws + OFF_WT12;  stride = 600; rowOff = 0;   colOff = 0;   break;
        case 2:  src = W2;  dst = ws + OFF_WT12;  stride = 600; rowOff = 0;   colOff = 300; break;
        case 3:  src = Wf1; dst = ws + OFF_WTF12; stride = 300; rowOff = 0;   colOff = 0;   break;
        default: src = Wf2; dst = ws + OFF_WTF12; stride = 300; rowOff = 300; colOff = 0;   break;
    }
    const int tx = threadIdx.x & 31, ty = threadIdx.x >> 5;
    #pragma unroll
    for (int r = 0; r < 4; ++r) {
        int g = tg * 32 + ty + r * 8, k = tk * 32 + tx;
        if (g < Dx && k < Dx) tile[ty + r * 8][tx] = ldf(src, g * Dx + k, isbf);
    }
    __syncthreads();
    #pragma unroll
    for (int r = 0; r < 4; ++r) {
        int k = tk * 32 + ty + r * 8, g = tg * 32 + tx;
        if (g < Dx && k < Dx) dst[(k + rowOff) * stride + colOff + g] = tile[tx][ty + r * 8];
    }
}

// ---------------------------------------------------------------------------
// k_repmap: rep = elu(X @ Wfc^T + bfc), coalesced via WTfc
// ---------------------------------------------------------------------------
__global__ __launch_bounds__(320) void k_repmap(
        const void* __restrict__ Xv, const void* __restrict__ Wdet,
        const float* __restrict__ ws_ro, float* __restrict__ rep) {
    const float* WT = ws_ro + OFF_WTFC;
    const float* bias = ws_ro + OFF_BIAS;
    __shared__ float Xs[4][304];
    __shared__ int s_isbf;
    const int tid = threadIdx.x, m0 = blockIdx.x * 4;
    if (tid == 0) s_isbf = detect_bf16(Wdet);
    __syncthreads();
    const int isbf = s_isbf;
    if (isbf) {
        const unsigned short* X = (const unsigned short*)Xv;
        for (int idx = tid; idx < 4 * Dx; idx += 320) {
            int r = idx / Dx, c = idx - r * Dx;
            Xs[r][c] = bf2f(X[m0 * Dx + idx]);
        }
    } else {
        const float* X = (const float*)Xv;
        for (int idx = tid; idx < 4 * Dx; idx += 320) {
            int r = idx / Dx, c = idx - r * Dx;
            Xs[r][c] = X[m0 * Dx + idx];
        }
    }
    __syncthreads();
    const int g = tid;
    if (g < Dx) {
        float a0 = 0.f, a1 = 0.f, a2 = 0.f, a3 = 0.f;
        const float* wp = WT + g;
        for (int k = 0; k < Dx; k += 4) {
            float w0 = wp[(k + 0) * 300], w1 = wp[(k + 1) * 300];
            float w2 = wp[(k + 2) * 300], w3 = wp[(k + 3) * 300];
            a0 += Xs[0][k] * w0 + Xs[0][k + 1] * w1 + Xs[0][k + 2] * w2 + Xs[0][k + 3] * w3;
            a1 += Xs[1][k] * w0 + Xs[1][k + 1] * w1 + Xs[1][k + 2] * w2 + Xs[1][k + 3] * w3;
            a2 += Xs[2][k] * w0 + Xs[2][k + 1] * w1 + Xs[2][k + 2] * w2 + Xs[2][k + 3] * w3;
            a3 += Xs[3][k] * w0 + Xs[3][k + 1] * w1 + Xs[3][k + 2] * w2 + Xs[3][k + 3] * w3;
        }
        float bb = bias[g];
        float acc[4] = {a0, a1, a2, a3};
        #pragma unroll
        for (int r = 0; r < 4; ++r) {
            float v = acc[r] + bb;
            v = v > 0.f ? v : (__expf(v) - 1.0f);
            rep[(m0 + r) * Dx + g] = v;
        }
    }
}

// ---------------------------------------------------------------------------
// k_dephead: dep = rep@W1^T + b1 ; head = rep@W2^T, coalesced via WT12
// ---------------------------------------------------------------------------
__global__ __launch_bounds__(640) void k_dephead(
        const float* __restrict__ ws_ro, float* __restrict__ ws) {
    const float* rep = ws_ro + OFF_REP;
    const float* WT  = ws_ro + OFF_WT12;
    const float* b1  = ws_ro + OFF_BIAS + 304;
    float* dep  = ws + OFF_DEP;
    float* head = ws + OFF_HEAD;
    __shared__ float Xs[4][304];
    const int tid = threadIdx.x, m0 = blockIdx.x * 4;
    for (int idx = tid; idx < 4 * Dx; idx += 640) {
        int r = idx / Dx, c = idx - r * Dx;
        Xs[r][c] = rep[m0 * Dx + idx];
    }
    __syncthreads();
    const int g = tid;
    if (g < 600) {
        float a0 = 0.f, a1 = 0.f, a2 = 0.f, a3 = 0.f;
        const float* wp = WT + g;
        for (int k = 0; k < Dx; k += 4) {
            float w0 = wp[(k + 0) * 600], w1 = wp[(k + 1) * 600];
            float w2 = wp[(k + 2) * 600], w3 = wp[(k + 3) * 600];
            a0 += Xs[0][k] * w0 + Xs[0][k + 1] * w1 + Xs[0][k + 2] * w2 + Xs[0][k + 3] * w3;
            a1 += Xs[1][k] * w0 + Xs[1][k + 1] * w1 + Xs[1][k + 2] * w2 + Xs[1][k + 3] * w3;
            a2 += Xs[2][k] * w0 + Xs[2][k + 1] * w1 + Xs[2][k + 2] * w2 + Xs[2][k + 3] * w3;
            a3 += Xs[3][k] * w0 + Xs[3][k + 1] * w1 + Xs[3][k + 2] * w2 + Xs[3][k + 3] * w3;
        }
        if (g < Dx) {
            float bb = b1[g];
            dep[(m0 + 0) * Dx + g] = a0 + bb;
            dep[(m0 + 1) * Dx + g] = a1 + bb;
            dep[(m0 + 2) * Dx + g] = a2 + bb;
            dep[(m0 + 3) * Dx + g] = a3 + bb;
        } else {
            const int gg = g - Dx;
            head[(m0 + 0) * Dx + gg] = a0;
            head[(m0 + 1) * Dx + gg] = a1;
            head[(m0 + 2) * Dx + gg] = a2;
            head[(m0 + 3) * Dx + gg] = a3;
        }
    }
}

// ---------------------------------------------------------------------------
// k_attn: block = (b, balanced pair of i-tiles {2p,2p+1} and {254-2p,255-2p}).
// Pass1: one shared suffix-max sweep (no transcendentals, tanh monotone).
// Pass2: dep/rep load shared across the 2 i's; uniform mask branch.
// ---------------------------------------------------------------------------
__global__ __launch_bounds__(320) void k_attn(
        const float* __restrict__ ws_ro, const int* __restrict__ mask,
        float* __restrict__ attn) {
    const float* dep  = ws_ro + OFF_DEP;
    const float* head = ws_ro + OFF_HEAD;
    const float* rep  = ws_ro + OFF_REP;
    __shared__ float mkf[256];
    const int b = blockIdx.x >> 6, p = blockIdx.x & 63;
    const int tid = threadIdx.x;
    if (tid < 256) mkf[tid] = (float)mask[b * 256 + tid];
    __syncthreads();
    const int d = tid;
    if (d >= Dx) return;
    const int base = b * 256;

    #pragma unroll
    for (int half = 0; half < 2; ++half) {
        const int i0 = half ? (254 - 2 * p) : (2 * p);
        const float hv0 = head[(base + i0) * Dx + d];
        const float hv1 = head[(base + i0 + 1) * Dx + d];

        // pass 1: shared suffix max over valid j (monotone tanh -> raw args)
        float run = -1e30f;
        for (int j = 255; j >= i0 + 2; --j) {
            float dv = dep[(base + j) * Dx + d];
            run = (mkf[j] != 0.f) ? fmaxf(run, dv) : run;
        }
        const float am1 = run;
        {
            float dv = dep[(base + i0 + 1) * Dx + d];
            run = (mkf[i0 + 1] != 0.f) ? fmaxf(run, dv) : run;
        }
        const float am0 = run;
        const float mv0 = fmaxf(0.f, CC * fast_tanh((am0 + hv0) * 0.2f));
        const float mv1 = fmaxf(0.f, CC * fast_tanh((am1 + hv1) * 0.2f));

        float s0 = 0.f, r0 = 0.f, s1 = 0.f, r1 = 0.f;
        // j = i0+1: only i0 attends
        {
            const int j = i0 + 1;
            if (mkf[j] != 0.f) {
                float dv = dep[(base + j) * Dx + d];
                float rv = rep[(base + j) * Dx + d];
                float u = __expf(0.4f * (dv + hv0));
                float l = CC * (u - 1.f) * __builtin_amdgcn_rcpf(u + 1.f);
                float e = __expf(l - mv0);
                s0 += e; r0 += e * rv;
            }
        }
        for (int j = i0 + 2; j < 256; ++j) {
            // unconditional loads: hoistable/pipelinable ahead of the branch
            float dv = dep[(base + j) * Dx + d];
            float rv = rep[(base + j) * Dx + d];
            if (mkf[j] != 0.f) {
                float u0 = __expf(0.4f * (dv + hv0));
                float l0 = CC * (u0 - 1.f) * __builtin_amdgcn_rcpf(u0 + 1.f);
                float e0 = __expf(l0 - mv0);
                s0 += e0; r0 += e0 * rv;
                float u1 = __expf(0.4f * (dv + hv1));
                float l1 = CC * (u1 - 1.f) * __builtin_amdgcn_rcpf(u1 + 1.f);
                float e1 = __expf(l1 - mv1);
                s1 += e1; r1 += e1 * rv;
            }
        }
        const float den0 = s0 + (s0 == 0.f ? 1.f : 0.f) + 1e-20f;
        const float den1 = s1 + (s1 == 0.f ? 1.f : 0.f) + 1e-20f;
        attn[(base + i0) * Dx + d]     = r0 / den0;
        attn[(base + i0 + 1) * Dx + d] = r1 / den1;
    }
}

// ---------------------------------------------------------------------------
// k_gate: gate = sigmoid([rep|attn] @ [Wf1|Wf2]^T + bf); blend; mask; store
// ---------------------------------------------------------------------------
__global__ __launch_bounds__(320) void k_gate(
        const float* __restrict__ ws_ro, const void* __restrict__ Wdet,
        const int* __restrict__ mask, void* __restrict__ outv) {
    const float* rep  = ws_ro + OFF_REP;
    const float* attn = ws_ro + OFF_ATTN;
    const float* WT   = ws_ro + OFF_WTF12;
    const float* bfp  = ws_ro + OFF_BIAS + 608;
    __shared__ float Xs[4][608];
    __shared__ int s_isbf;
    const int tid = threadIdx.x, m0 = blockIdx.x * 4;
    if (tid == 0) s_isbf = detect_bf16(Wdet);
    for (int idx = tid; idx < 4 * Dx; idx += 320) {
        int r = idx / Dx, c = idx - r * Dx;
        Xs[r][c]       = rep[m0 * Dx + idx];
        Xs[r][Dx + c]  = attn[m0 * Dx + idx];
    }
    __syncthreads();
    const int isbf = s_isbf, g = tid;
    if (g < Dx) {
        float a0 = 0.f, a1 = 0.f, a2 = 0.f, a3 = 0.f;
        const float* wp = WT + g;
        for (int k = 0; k < 600; k += 4) {
            float w0 = wp[(k + 0) * 300], w1 = wp[(k + 1) * 300];
            float w2 = wp[(k + 2) * 300], w3 = wp[(k + 3) * 300];
            a0 += Xs[0][k] * w0 + Xs[0][k + 1] * w1 + Xs[0][k + 2] * w2 + Xs[0][k + 3] * w3;
            a1 += Xs[1][k] * w0 + Xs[1][k + 1] * w1 + Xs[1][k + 2] * w2 + Xs[1][k + 3] * w3;
            a2 += Xs[2][k] * w0 + Xs[2][k + 1] * w1 + Xs[2][k + 2] * w2 + Xs[2][k + 3] * w3;
            a3 += Xs[3][k] * w0 + Xs[3][k + 1] * w1 + Xs[3][k + 2] * w2 + Xs[3][k + 3] * w3;
        }
        float bb = bfp[g];
        float acc[4] = {a0, a1, a2, a3};
        #pragma unroll
        for (int r = 0; r < 4; ++r) {
            float gp = acc[r] + bb;
            float gate = 1.0f / (1.0f + __expf(-gp));
            float rv = Xs[r][g];
            float av = Xs[r][Dx + g];
            float res = (gate * rv + (1.0f - gate) * av) * (float)mask[m0 + r];
            if (isbf) ((__hip_bfloat16*)outv)[(m0 + r) * Dx + g] = __float2bfloat16(res);
            else      ((float*)outv)[(m0 + r) * Dx + g] = res;
        }
    }
}

extern "C" void kernel_launch(void* const* d_in, const int* in_sizes, int n_in,
                              void* d_out, int out_size, void* d_ws, size_t ws_size,
                              hipStream_t stream) {
    const void* X   = d_in[0];
    const int*  msk = (const int*)d_in[1];
    const void* Wfc = d_in[2];
    const void* bfc = d_in[3];
    const void* W1  = d_in[4];
    const void* W2  = d_in[5];
    const void* b1  = d_in[6];
    const void* Wf1 = d_in[7];
    const void* Wf2 = d_in[8];
    const void* bfv = d_in[9];

    float* ws = (float*)d_ws;

    hipLaunchKernelGGL(k_prep,    dim3(501), dim3(256), 0, stream,
                       Wfc, W1, W2, Wf1, Wf2, bfc, b1, bfv, ws);
    hipLaunchKernelGGL(k_repmap,  dim3(Mx / 4), dim3(320), 0, stream,
                       X, Wfc, ws, ws + OFF_REP);
    hipLaunchKernelGGL(k_dephead, dim3(Mx / 4), dim3(640), 0, stream, ws, ws);
    hipLaunchKernelGGL(k_attn,    dim3(256), dim3(320), 0, stream,
                       ws, msk, ws + OFF_ATTN);
    hipLaunchKernelGGL(k_gate,    dim3(Mx / 4), dim3(320), 0, stream,
                       ws, Wf1, msk, d_out);
}

// Round 4
// 199.734 us; speedup vs baseline: 1.3880x; 1.3880x over previous
//
#include <hip/hip_runtime.h>
#include <hip/hip_bf16.h>

#define Sx 256
#define Dx 300
#define Mx 1024
#define CC 5.0f

// workspace layout (float offsets)
#define OFF_REP    0
#define OFF_DEP    307200
#define OFF_HEAD   614400
#define OFF_ATTN   921600
#define OFF_WTFC   1228800   // [300k][300g]
#define OFF_WT12   1318800   // [300k][600g]  g<300: W1 (dep), g>=300: W2 (head)
#define OFF_WTF12  1498800   // [600k][300g]  k<300: Wf1, k>=300: Wf2
#define OFF_BIAS   1678800   // bfc@+0, b1@+304, bf@+608

__device__ __forceinline__ float bf2f(unsigned short u) {
    union { unsigned int i; float f; } v;
    v.i = ((unsigned int)u) << 16;
    return v.f;
}

// weights ~N(0,0.05): bf16 interp of true bf16 -> all |v|<1; fp32 halves -> ~2e-10
__device__ __forceinline__ int detect_bf16(const void* w) {
    const unsigned short* u = (const unsigned short*)w;
    int ok = 1;
    #pragma unroll
    for (int t = 0; t < 64; ++t) {
        float v = bf2f(u[t]);
        ok &= (fabsf(v) < 1.0f) ? 1 : 0;
    }
    return ok;
}

__device__ __forceinline__ float ldf(const void* p, int idx, int isbf) {
    return isbf ? bf2f(((const unsigned short*)p)[idx]) : ((const float*)p)[idx];
}

// ---------------------------------------------------------------------------
// k_prep: transpose 5 weight matrices into fp32 WT layouts + biases.
// ---------------------------------------------------------------------------
__global__ __launch_bounds__(256) void k_prep(
        const void* __restrict__ Wfc, const void* __restrict__ W1,
        const void* __restrict__ W2,  const void* __restrict__ Wf1,
        const void* __restrict__ Wf2, const void* __restrict__ bfc,
        const void* __restrict__ b1,  const void* __restrict__ bfv,
        float* __restrict__ ws) {
    __shared__ float tile[32][33];
    __shared__ int s_isbf;
    if (threadIdx.x == 0) s_isbf = detect_bf16(Wfc);
    __syncthreads();
    const int isbf = s_isbf;
    const int bid = blockIdx.x;
    if (bid == 500) {
        for (int idx = threadIdx.x; idx < 912; idx += 256) {
            int wb = idx / 304, o = idx - wb * 304;
            const void* src = (wb == 0) ? bfc : (wb == 1 ? b1 : bfv);
            ws[OFF_BIAS + idx] = (o < Dx) ? ldf(src, o, isbf) : 0.0f;
        }
        return;
    }
    const int job = bid / 100, t = bid % 100;
    const int tg = t / 10, tk = t % 10;
    const void* src; float* dst; int stride, rowOff, colOff;
    switch (job) {
        case 0:  src = Wfc; dst = ws + OFF_WTFC;  stride = 300; rowOff = 0;   colOff = 0;   break;
        case 1:  src = W1;  dst = ws + OFF_WT12;  stride = 600; rowOff = 0;   colOff = 0;   break;
        case 2:  src = W2;  dst = ws + OFF_WT12;  stride = 600; rowOff = 0;   colOff = 300; break;
        case 3:  src = Wf1; dst = ws + OFF_WTF12; stride = 300; rowOff = 0;   colOff = 0;   break;
        default: src = Wf2; dst = ws + OFF_WTF12; stride = 300; rowOff = 300; colOff = 0;   break;
    }
    const int tx = threadIdx.x & 31, ty = threadIdx.x >> 5;
    #pragma unroll
    for (int r = 0; r < 4; ++r) {
        int g = tg * 32 + ty + r * 8, k = tk * 32 + tx;
        if (g < Dx && k < Dx) tile[ty + r * 8][tx] = ldf(src, g * Dx + k, isbf);
    }
    __syncthreads();
    #pragma unroll
    for (int r = 0; r < 4; ++r) {
        int k = tk * 32 + ty + r * 8, g = tg * 32 + tx;
        if (g < Dx && k < Dx) dst[(k + rowOff) * stride + colOff + g] = tile[tx][ty + r * 8];
    }
}

// ---------------------------------------------------------------------------
// k_repmap: rep = elu(X @ Wfc^T + bfc), coalesced via WTfc, float4 LDS reads
// ---------------------------------------------------------------------------
__global__ __launch_bounds__(320) void k_repmap(
        const void* __restrict__ Xv, const void* __restrict__ Wdet,
        const float* __restrict__ ws_ro, float* __restrict__ rep) {
    const float* WT = ws_ro + OFF_WTFC;
    const float* bias = ws_ro + OFF_BIAS;
    __shared__ __align__(16) float Xs[4][304];
    __shared__ int s_isbf;
    const int tid = threadIdx.x, m0 = blockIdx.x * 4;
    if (tid == 0) s_isbf = detect_bf16(Wdet);
    __syncthreads();
    const int isbf = s_isbf;
    if (isbf) {
        const unsigned short* X = (const unsigned short*)Xv;
        for (int idx = tid; idx < 4 * Dx; idx += 320) {
            int r = idx / Dx, c = idx - r * Dx;
            Xs[r][c] = bf2f(X[m0 * Dx + idx]);
        }
    } else {
        const float* X = (const float*)Xv;
        for (int idx = tid; idx < 4 * Dx; idx += 320) {
            int r = idx / Dx, c = idx - r * Dx;
            Xs[r][c] = X[m0 * Dx + idx];
        }
    }
    __syncthreads();
    const int g = tid;
    if (g < Dx) {
        float a0 = 0.f, a1 = 0.f, a2 = 0.f, a3 = 0.f;
        const float* wp = WT + g;
        #pragma unroll 2
        for (int k = 0; k < Dx; k += 4) {
            float w0 = wp[(k + 0) * 300], w1 = wp[(k + 1) * 300];
            float w2 = wp[(k + 2) * 300], w3 = wp[(k + 3) * 300];
            float4 x0 = *(const float4*)(&Xs[0][k]);
            float4 x1 = *(const float4*)(&Xs[1][k]);
            float4 x2 = *(const float4*)(&Xs[2][k]);
            float4 x3 = *(const float4*)(&Xs[3][k]);
            a0 += x0.x * w0 + x0.y * w1 + x0.z * w2 + x0.w * w3;
            a1 += x1.x * w0 + x1.y * w1 + x1.z * w2 + x1.w * w3;
            a2 += x2.x * w0 + x2.y * w1 + x2.z * w2 + x2.w * w3;
            a3 += x3.x * w0 + x3.y * w1 + x3.z * w2 + x3.w * w3;
        }
        float bb = bias[g];
        float acc[4] = {a0, a1, a2, a3};
        #pragma unroll
        for (int r = 0; r < 4; ++r) {
            float v = acc[r] + bb;
            v = v > 0.f ? v : (__expf(v) - 1.0f);
            rep[(m0 + r) * Dx + g] = v;
        }
    }
}

// ---------------------------------------------------------------------------
// k_dephead: dep = rep@W1^T + b1 ; head = rep@W2^T
// ---------------------------------------------------------------------------
__global__ __launch_bounds__(640) void k_dephead(
        const float* __restrict__ ws_ro, float* __restrict__ ws) {
    const float* rep = ws_ro + OFF_REP;
    const float* WT  = ws_ro + OFF_WT12;
    const float* b1  = ws_ro + OFF_BIAS + 304;
    float* dep  = ws + OFF_DEP;
    float* head = ws + OFF_HEAD;
    __shared__ __align__(16) float Xs[4][304];
    const int tid = threadIdx.x, m0 = blockIdx.x * 4;
    for (int idx = tid; idx < 4 * Dx; idx += 640) {
        int r = idx / Dx, c = idx - r * Dx;
        Xs[r][c] = rep[m0 * Dx + idx];
    }
    __syncthreads();
    const int g = tid;
    if (g < 600) {
        float a0 = 0.f, a1 = 0.f, a2 = 0.f, a3 = 0.f;
        const float* wp = WT + g;
        #pragma unroll 2
        for (int k = 0; k < Dx; k += 4) {
            float w0 = wp[(k + 0) * 600], w1 = wp[(k + 1) * 600];
            float w2 = wp[(k + 2) * 600], w3 = wp[(k + 3) * 600];
            float4 x0 = *(const float4*)(&Xs[0][k]);
            float4 x1 = *(const float4*)(&Xs[1][k]);
            float4 x2 = *(const float4*)(&Xs[2][k]);
            float4 x3 = *(const float4*)(&Xs[3][k]);
            a0 += x0.x * w0 + x0.y * w1 + x0.z * w2 + x0.w * w3;
            a1 += x1.x * w0 + x1.y * w1 + x1.z * w2 + x1.w * w3;
            a2 += x2.x * w0 + x2.y * w1 + x2.z * w2 + x2.w * w3;
            a3 += x3.x * w0 + x3.y * w1 + x3.z * w2 + x3.w * w3;
        }
        if (g < Dx) {
            float bb = b1[g];
            dep[(m0 + 0) * Dx + g] = a0 + bb;
            dep[(m0 + 1) * Dx + g] = a1 + bb;
            dep[(m0 + 2) * Dx + g] = a2 + bb;
            dep[(m0 + 3) * Dx + g] = a3 + bb;
        } else {
            const int gg = g - Dx;
            head[(m0 + 0) * Dx + gg] = a0;
            head[(m0 + 1) * Dx + gg] = a1;
            head[(m0 + 2) * Dx + gg] = a2;
            head[(m0 + 3) * Dx + gg] = a3;
        }
    }
}

// ---------------------------------------------------------------------------
// k_attn: SINGLE PASS, branchless. Fixed softmax shift m=C=5 (logits <= C,
// exp(l-5) in [4.5e-5, 1] -> no under/overflow; identical after normalize).
// 2-i tiles, long/short interleaved, grid 512 (2 blocks/CU, 10 waves/CU).
// ---------------------------------------------------------------------------
__global__ __launch_bounds__(320) void k_attn(
        const float* __restrict__ ws_ro, const int* __restrict__ mask,
        float* __restrict__ attn) {
    const float* dep  = ws_ro + OFF_DEP;
    const float* head = ws_ro + OFF_HEAD;
    const float* rep  = ws_ro + OFF_REP;
    __shared__ float mkf[256];
    const int blk = blockIdx.x;
    const int b = blk >> 7;              // 0..3
    const int tile = blk & 127;          // 0..127, alternating long/short
    const int u = tile >> 1;
    const int i0 = (tile & 1) ? (254 - 2 * u) : (2 * u);
    const int tid = threadIdx.x;
    if (tid < 256) mkf[tid] = (float)mask[b * 256 + tid];
    __syncthreads();
    const int d = tid;
    if (d >= Dx) return;
    const int base = b * 256;

    const float hv0 = head[(base + i0) * Dx + d];
    const float hv1 = head[(base + i0 + 1) * Dx + d];
    const float pw0 = __expf(0.4f * hv0);   // e^{0.4 hv}
    const float pw1 = __expf(0.4f * hv1);

    float s0 = 0.f, r0 = 0.f, s1 = 0.f, r1 = 0.f;

    // j = i0+1: attends to i0 only
    {
        const int j = i0 + 1;
        float dv = dep[(base + j) * Dx + d];
        float rv = rep[(base + j) * Dx + d];
        float mk = mkf[j];
        float ex = __expf(0.4f * dv);
        float u0 = fmaf(ex, pw0, 1.0f);            // e^{0.4(dv+hv)} + 1
        float e0 = __expf(-10.0f * __builtin_amdgcn_rcpf(u0));  // exp(l-5)
        float em0 = e0 * mk;
        s0 += em0; r0 = fmaf(em0, rv, r0);
    }
    const float* dp = dep + base * Dx + d;
    const float* rp = rep + base * Dx + d;
    #pragma unroll 4
    for (int j = i0 + 2; j < 256; ++j) {
        float dv = dp[j * Dx];
        float rv = rp[j * Dx];
        float mk = mkf[j];
        float ex = __expf(0.4f * dv);              // shared across i's
        float u0 = fmaf(ex, pw0, 1.0f);
        float u1 = fmaf(ex, pw1, 1.0f);
        float e0 = __expf(-10.0f * __builtin_amdgcn_rcpf(u0));
        float e1 = __expf(-10.0f * __builtin_amdgcn_rcpf(u1));
        float em0 = e0 * mk;
        float em1 = e1 * mk;
        s0 += em0; r0 = fmaf(em0, rv, r0);
        s1 += em1; r1 = fmaf(em1, rv, r1);
    }
    const float den0 = s0 + (s0 == 0.f ? 1.f : 0.f) + 1e-20f;
    const float den1 = s1 + (s1 == 0.f ? 1.f : 0.f) + 1e-20f;
    attn[(base + i0) * Dx + d]     = r0 / den0;
    attn[(base + i0 + 1) * Dx + d] = r1 / den1;
}

// ---------------------------------------------------------------------------
// k_gate: gate = sigmoid([rep|attn] @ [Wf1|Wf2]^T + bf); blend; mask; store
// ---------------------------------------------------------------------------
__global__ __launch_bounds__(320) void k_gate(
        const float* __restrict__ ws_ro, const void* __restrict__ Wdet,
        const int* __restrict__ mask, void* __restrict__ outv) {
    const float* rep  = ws_ro + OFF_REP;
    const float* attn = ws_ro + OFF_ATTN;
    const float* WT   = ws_ro + OFF_WTF12;
    const float* bfp  = ws_ro + OFF_BIAS + 608;
    __shared__ __align__(16) float Xs[4][608];
    __shared__ int s_isbf;
    const int tid = threadIdx.x, m0 = blockIdx.x * 4;
    if (tid == 0) s_isbf = detect_bf16(Wdet);
    for (int idx = tid; idx < 4 * Dx; idx += 320) {
        int r = idx / Dx, c = idx - r * Dx;
        Xs[r][c]       = rep[m0 * Dx + idx];
        Xs[r][Dx + c]  = attn[m0 * Dx + idx];
    }
    __syncthreads();
    const int isbf = s_isbf, g = tid;
    if (g < Dx) {
        float a0 = 0.f, a1 = 0.f, a2 = 0.f, a3 = 0.f;
        const float* wp = WT + g;
        #pragma unroll 2
        for (int k = 0; k < 600; k += 4) {
            float w0 = wp[(k + 0) * 300], w1 = wp[(k + 1) * 300];
            float w2 = wp[(k + 2) * 300], w3 = wp[(k + 3) * 300];
            float4 x0 = *(const float4*)(&Xs[0][k]);
            float4 x1 = *(const float4*)(&Xs[1][k]);
            float4 x2 = *(const float4*)(&Xs[2][k]);
            float4 x3 = *(const float4*)(&Xs[3][k]);
            a0 += x0.x * w0 + x0.y * w1 + x0.z * w2 + x0.w * w3;
            a1 += x1.x * w0 + x1.y * w1 + x1.z * w2 + x1.w * w3;
            a2 += x2.x * w0 + x2.y * w1 + x2.z * w2 + x2.w * w3;
            a3 += x3.x * w0 + x3.y * w1 + x3.z * w2 + x3.w * w3;
        }
        float bb = bfp[g];
        float acc[4] = {a0, a1, a2, a3};
        #pragma unroll
        for (int r = 0; r < 4; ++r) {
            float gp = acc[r] + bb;
            float gate = 1.0f / (1.0f + __expf(-gp));
            float rv = Xs[r][g];
            float av = Xs[r][Dx + g];
            float res = (gate * rv + (1.0f - gate) * av) * (float)mask[m0 + r];
            if (isbf) ((__hip_bfloat16*)outv)[(m0 + r) * Dx + g] = __float2bfloat16(res);
            else      ((float*)outv)[(m0 + r) * Dx + g] = res;
        }
    }
}

extern "C" void kernel_launch(void* const* d_in, const int* in_sizes, int n_in,
                              void* d_out, int out_size, void* d_ws, size_t ws_size,
                              hipStream_t stream) {
    const void* X   = d_in[0];
    const int*  msk = (const int*)d_in[1];
    const void* Wfc = d_in[2];
    const void* bfc = d_in[3];
    const void* W1  = d_in[4];
    const void* W2  = d_in[5];
    const void* b1  = d_in[6];
    const void* Wf1 = d_in[7];
    const void* Wf2 = d_in[8];
    const void* bfv = d_in[9];

    float* ws = (float*)d_ws;

    hipLaunchKernelGGL(k_prep,    dim3(501), dim3(256), 0, stream,
                       Wfc, W1, W2, Wf1, Wf2, bfc, b1, bfv, ws);
    hipLaunchKernelGGL(k_repmap,  dim3(Mx / 4), dim3(320), 0, stream,
                       X, Wfc, ws, ws + OFF_REP);
    hipLaunchKernelGGL(k_dephead, dim3(Mx / 4), dim3(640), 0, stream, ws, ws);
    hipLaunchKernelGGL(k_attn,    dim3(512), dim3(320), 0, stream,
                       ws, msk, ws + OFF_ATTN);
    hipLaunchKernelGGL(k_gate,    dim3(Mx / 4), dim3(320), 0, stream,
                       ws, Wf1, msk, d_out);
}